// Round 1
// baseline (470.582 us; speedup 1.0000x reference)
//
#include <hip/hip_runtime.h>
#include <stdint.h>
#include <stddef.h>

#define LN_EPS 1e-5f

typedef __bf16 bf16;
typedef __bf16 bf16x8 __attribute__((ext_vector_type(8)));
typedef __bf16 bf16x4 __attribute__((ext_vector_type(4)));
typedef float f32x4 __attribute__((ext_vector_type(4)));

// async global->LDS, 16B per lane. LDS dest must be wave-uniform base + lane*16.
#define GL16(gp, lp)                                                                   \
  __builtin_amdgcn_global_load_lds((__attribute__((address_space(1))) uint32_t*)(gp),  \
                                   (__attribute__((address_space(3))) uint32_t*)(lp),  \
                                   16, 0, 0)

// ---------------------------------------------------------------------------
// fp32 -> bf16 convert (vectorized float4 -> bf16x4)
// ---------------------------------------------------------------------------
__global__ __launch_bounds__(256) void cvt_kernel(const float* __restrict__ src,
                                                  bf16* __restrict__ dst, int n4) {
  int i = blockIdx.x * 256 + threadIdx.x;
  if (i >= n4) return;
  const float4 v = ((const float4*)src)[i];
  bf16x4 o;
  o[0] = (bf16)v.x; o[1] = (bf16)v.y; o[2] = (bf16)v.z; o[3] = (bf16)v.w;
  ((bf16x4*)dst)[i] = o;
}

// ---------------------------------------------------------------------------
// Shared GEMM core: C[128x128] tile, A [M,768] bf16 row-major, B [Nn,768] bf16
// row-major (B^T GEMM: C[m,n] = sum_k A[m,k]*B[n,k]). K=768, BK=32.
// 256 threads = 4 waves, each wave 64x64 via 4x4 mfma_f32_16x16x32_bf16.
// m97 structure: global_load_lds(16B) staging + 2-barrier K-loop.
// ---------------------------------------------------------------------------
__device__ __forceinline__ void gemm_core_768(const bf16* __restrict__ At,   // + m0*768
                                              const bf16* __restrict__ Bt,   // + n0*768
                                              bf16* lA, bf16* lB,
                                              f32x4 acc[4][4]) {
  const int tid  = threadIdx.x;
  const int wave = tid >> 6;
  const int lane = tid & 63;
  const int l16  = lane & 15;

  // staging: wave w covers rows [32w, 32w+32) of the 128-row tile.
  // lane l -> row 32w + l/4 (+16 for second inst), col (l%4)*8 bf16.
  const int srow = wave * 32 + (lane >> 2);
  const int scol = (lane & 3) * 8;
  const bf16* gA0 = At + srow * 768 + scol;
  const bf16* gA1 = gA0 + 16 * 768;
  const bf16* gB0 = Bt + srow * 768 + scol;
  const bf16* gB1 = gB0 + 16 * 768;
  // LDS row-major [128][32] bf16; lane's 16B lands at base + lane*16B (contiguous).
  bf16* sA0 = lA + wave * 1024 + lane * 8;
  bf16* sA1 = sA0 + 512;
  bf16* sB0 = lB + wave * 1024 + lane * 8;
  bf16* sB1 = sB0 + 512;

  const int wm   = (wave & 1) * 64;
  const int wn   = (wave >> 1) * 64;
  const int koff = (lane >> 4) * 8;   // quad*8 k-offset for A/B fragments

  for (int kt = 0; kt < 768; kt += 32) {
    GL16(gA0 + kt, sA0);
    GL16(gA1 + kt, sA1);
    GL16(gB0 + kt, sB0);
    GL16(gB1 + kt, sB1);
    __syncthreads();   // drains vmcnt(0) then barrier: staged data visible

    bf16x8 aF[4], bF[4];
#pragma unroll
    for (int i = 0; i < 4; i++)
      aF[i] = *(const bf16x8*)(lA + (wm + i * 16 + l16) * 32 + koff);
#pragma unroll
    for (int j = 0; j < 4; j++)
      bF[j] = *(const bf16x8*)(lB + (wn + j * 16 + l16) * 32 + koff);

#pragma unroll
    for (int i = 0; i < 4; i++)
#pragma unroll
      for (int j = 0; j < 4; j++)
        acc[i][j] = __builtin_amdgcn_mfma_f32_16x16x32_bf16(aF[i], bF[j], acc[i][j], 0, 0, 0);

    __syncthreads();   // all waves done reading LDS before next stage overwrites
  }
}

// ---------------------------------------------------------------------------
// GEMM1: qkv[32768, 2304] bf16 = x_bf16[32768,768] @ w_qkv_bf16[2304,768]^T
// ---------------------------------------------------------------------------
__global__ __launch_bounds__(256) void gemm_qkv(const bf16* __restrict__ A,
                                                const bf16* __restrict__ B,
                                                bf16* __restrict__ C) {
  __shared__ __align__(16) bf16 lA[128 * 32];
  __shared__ __align__(16) bf16 lB[128 * 32];
  f32x4 acc[4][4] = {};

  const int m0 = blockIdx.x * 128;
  const int n0 = blockIdx.y * 128;
  gemm_core_768(A + (size_t)m0 * 768, B + (size_t)n0 * 768, lA, lB, acc);

  const int tid = threadIdx.x, wave = tid >> 6, lane = tid & 63;
  // C/D layout (16x16x32): col = lane&15, row = (lane>>4)*4 + reg
  const int row0 = m0 + (wave & 1) * 64 + (lane >> 4) * 4;
  const int col0 = n0 + (wave >> 1) * 64 + (lane & 15);
#pragma unroll
  for (int i = 0; i < 4; i++)
#pragma unroll
    for (int j = 0; j < 4; j++)
#pragma unroll
      for (int r = 0; r < 4; r++)
        C[(size_t)(row0 + i * 16 + r) * 2304 + col0 + j * 16] = (bf16)acc[i][j][r];
}

// ---------------------------------------------------------------------------
// modulator[b,h,d] = LN_d( sum_n p2[h,n] * k[b,h,n,d] * v[b,h,n,d] )
// grid (12, 8) = (h, b); 256 threads: d = t&63, n-chunk = t>>6 (4 x 1024)
// ---------------------------------------------------------------------------
__global__ __launch_bounds__(256) void modulator_ln(const bf16* __restrict__ qkv,
                                                    const float* __restrict__ p2,
                                                    const float* __restrict__ gamma,
                                                    const float* __restrict__ beta,
                                                    float* __restrict__ mod) {
  const int h = blockIdx.x, b = blockIdx.y;
  const int t = threadIdx.x;
  const int d = t & 63, ch = t >> 6;

  const bf16* kp = qkv + (size_t)(b * 4096 + ch * 1024) * 2304 + 768 + h * 64 + d;
  const float* p2p = p2 + h * 4096 + ch * 1024;
  float acc = 0.f;
#pragma unroll 8
  for (int n = 0; n < 1024; n++) {
    float kk = (float)kp[0];
    float vv = (float)kp[768];   // v is +768 cols from k
    acc += p2p[n] * kk * vv;
    kp += 2304;
  }

  __shared__ float red[4][64];
  red[ch][d] = acc;
  __syncthreads();
  if (t < 64) {   // exactly wave 0
    float s = red[0][d] + red[1][d] + red[2][d] + red[3][d];
    float sum = s, sumsq = s * s;
#pragma unroll
    for (int o = 32; o > 0; o >>= 1) {
      sum   += __shfl_xor(sum, o);
      sumsq += __shfl_xor(sumsq, o);
    }
    const float mu  = sum * (1.f / 64.f);
    const float var = sumsq * (1.f / 64.f) - mu * mu;
    const float r   = rsqrtf(var + LN_EPS);
    mod[(b * 12 + h) * 64 + d] = (s - mu) * r * gamma[d] + beta[d];
  }
}

// ---------------------------------------------------------------------------
// a_mod[m, c] = q[m, c] * p1[h(c), n(m)] * mod[b(m), c]   (bf16 out)
// m = b*4096+n, c = h*64+d; vectorized 8 bf16 per thread.
// ---------------------------------------------------------------------------
__global__ __launch_bounds__(256) void modulate(const bf16* __restrict__ qkv,
                                                const float* __restrict__ p1,
                                                const float* __restrict__ mod,
                                                bf16* __restrict__ amod) {
  const int v = blockIdx.x * 256 + threadIdx.x;   // vec-8 index; total 32768*96
  if (v >= 32768 * 96) return;
  const int m  = v / 96;
  const int cv = v - m * 96;
  const int c0 = cv * 8;          // 8 consecutive c stay within one head (64|c blocks)
  const int b  = m >> 12;
  const int n  = m & 4095;
  const int h  = c0 >> 6;

  const bf16x8 q = *(const bf16x8*)(qkv + (size_t)m * 2304 + c0);
  const float pv = p1[h * 4096 + n];
  const float4 m0 = *(const float4*)(mod + b * 768 + c0);
  const float4 m1 = *(const float4*)(mod + b * 768 + c0 + 4);

  bf16x8 o;
  o[0] = (bf16)((float)q[0] * pv * m0.x);
  o[1] = (bf16)((float)q[1] * pv * m0.y);
  o[2] = (bf16)((float)q[2] * pv * m0.z);
  o[3] = (bf16)((float)q[3] * pv * m0.w);
  o[4] = (bf16)((float)q[4] * pv * m1.x);
  o[5] = (bf16)((float)q[5] * pv * m1.y);
  o[6] = (bf16)((float)q[6] * pv * m1.z);
  o[7] = (bf16)((float)q[7] * pv * m1.w);
  *(bf16x8*)(amod + (size_t)m * 768 + c0) = o;
}

// ---------------------------------------------------------------------------
// GEMM2: out[32768,768] fp32 = a_mod[32768,768] @ w_proj_bf16[768,768]^T + b_proj
// ---------------------------------------------------------------------------
__global__ __launch_bounds__(256) void gemm_proj(const bf16* __restrict__ A,
                                                 const bf16* __restrict__ B,
                                                 const float* __restrict__ bias,
                                                 float* __restrict__ C) {
  __shared__ __align__(16) bf16 lA[128 * 32];
  __shared__ __align__(16) bf16 lB[128 * 32];
  f32x4 acc[4][4] = {};

  const int m0 = blockIdx.x * 128;
  const int n0 = blockIdx.y * 128;
  gemm_core_768(A + (size_t)m0 * 768, B + (size_t)n0 * 768, lA, lB, acc);

  const int tid = threadIdx.x, wave = tid >> 6, lane = tid & 63;
  const int row0 = m0 + (wave & 1) * 64 + (lane >> 4) * 4;
  const int col0 = n0 + (wave >> 1) * 64 + (lane & 15);
#pragma unroll
  for (int j = 0; j < 4; j++) {
    const int col = col0 + j * 16;
    const float bv = bias[col];
#pragma unroll
    for (int i = 0; i < 4; i++)
#pragma unroll
      for (int r = 0; r < 4; r++)
        C[(size_t)(row0 + i * 16 + r) * 768 + col] = acc[i][j][r] + bv;
  }
}

// ---------------------------------------------------------------------------
extern "C" void kernel_launch(void* const* d_in, const int* in_sizes, int n_in,
                              void* d_out, int out_size, void* d_ws, size_t ws_size,
                              hipStream_t stream) {
  (void)in_sizes; (void)n_in; (void)out_size; (void)ws_size;

  const float* x      = (const float*)d_in[0];   // [8,4096,768]
  const float* w_qkv  = (const float*)d_in[1];   // [2304,768]
  const float* w_proj = (const float*)d_in[2];   // [768,768]
  const float* b_proj = (const float*)d_in[3];   // [768]
  const float* p1     = (const float*)d_in[4];   // [12,4096]
  const float* p2     = (const float*)d_in[5];   // [12,4096]
  const float* gamma  = (const float*)d_in[6];   // [64]
  const float* beta   = (const float*)d_in[7];   // [64]
  float* out = (float*)d_out;                    // [8,4096,768] fp32

  char* ws = (char*)d_ws;
  // workspace layout (bytes); total ~206 MB
  bf16*  xb   = (bf16*)(ws + 0);                  // 50,331,648  x bf16 [32768,768]
  bf16*  wqb  = (bf16*)(ws + 50331648);           //  3,538,944  w_qkv bf16 [2304,768]
  bf16*  wpb  = (bf16*)(ws + 53870592);           //  1,179,648  w_proj bf16 [768,768]
  bf16*  qkv  = (bf16*)(ws + 55050240);           // 150,994,944 qkv bf16 [32768,2304]
  float* mod  = (float*)(ws + 206045184);         //     24,576  mod fp32 [8,12,64]
  bf16*  amod = (bf16*)(ws + 0);                  // reuses xb region after gemm_qkv

  // 1) fp32 -> bf16 conversions
  cvt_kernel<<<24576, 256, 0, stream>>>(x, xb, 6291456);        // 25,165,824/4
  cvt_kernel<<<1728,  256, 0, stream>>>(w_qkv, wqb, 442368);    //  1,769,472/4
  cvt_kernel<<<576,   256, 0, stream>>>(w_proj, wpb, 147456);   //    589,824/4

  // 2) QKV GEMM: [32768,768] x [2304,768]^T -> [32768,2304] bf16
  gemm_qkv<<<dim3(256, 18), 256, 0, stream>>>(xb, wqb, qkv);

  // 3) modulator reduction + LayerNorm -> mod [8,12,64] fp32
  modulator_ln<<<dim3(12, 8), 256, 0, stream>>>(qkv, p2, gamma, beta, mod);

  // 4) a_mod = q * p1 * mod (bf16), overwrites xb region
  modulate<<<12288, 256, 0, stream>>>(qkv, p1, mod, amod);

  // 5) proj GEMM + bias: [32768,768] x [768,768]^T -> out fp32
  gemm_proj<<<dim3(256, 6), 256, 0, stream>>>(amod, wpb, b_proj, out);
}

// Round 2
// 436.206 us; speedup vs baseline: 1.0788x; 1.0788x over previous
//
#include <hip/hip_runtime.h>
#include <stdint.h>
#include <stddef.h>

#define LN_EPS 1e-5f

typedef __bf16 bf16;
typedef __bf16 bf16x8 __attribute__((ext_vector_type(8)));
typedef __bf16 bf16x4 __attribute__((ext_vector_type(4)));
typedef float f32x4 __attribute__((ext_vector_type(4)));

// async global->LDS, 16B per lane. LDS dest must be wave-uniform base + lane*16.
#define GL16(gp, lp)                                                                   \
  __builtin_amdgcn_global_load_lds((__attribute__((address_space(1))) uint32_t*)(gp),  \
                                   (__attribute__((address_space(3))) uint32_t*)(lp),  \
                                   16, 0, 0)

// ---------------------------------------------------------------------------
// fp32 -> bf16 convert (vectorized float4 -> bf16x4)
// ---------------------------------------------------------------------------
__global__ __launch_bounds__(256) void cvt_kernel(const float* __restrict__ src,
                                                  bf16* __restrict__ dst, int n4) {
  int i = blockIdx.x * 256 + threadIdx.x;
  if (i >= n4) return;
  const float4 v = ((const float4*)src)[i];
  bf16x4 o;
  o[0] = (bf16)v.x; o[1] = (bf16)v.y; o[2] = (bf16)v.z; o[3] = (bf16)v.w;
  ((bf16x4*)dst)[i] = o;
}

// ---------------------------------------------------------------------------
// Shared GEMM core: C[128x128] tile, A [M,768] bf16 row-major, B [Nn,768] bf16
// row-major (B^T GEMM). K=768, BK=32. 256 thr = 4 waves, 4x4 mfma 16x16x32.
// LDS tile [128 rows][4 chunks of 8 bf16]. Bank-conflict XOR swizzle:
//   LDS slot (r, q) holds global chunk (r, q ^ ((r>>1)&3)).
// ds_read_b128 then spreads 8 requests/bank-group -> conflict-free (was 8-way).
// ---------------------------------------------------------------------------
__device__ __forceinline__ void gemm_core_768(const bf16* __restrict__ At,   // + m0*768
                                              const bf16* __restrict__ Bt,   // + n0*768
                                              bf16* lA, bf16* lB,
                                              f32x4 acc[4][4]) {
  const int tid  = threadIdx.x;
  const int wave = tid >> 6;
  const int lane = tid & 63;
  const int l16  = lane & 15;

  // staging: wave w covers rows [32w, 32w+32). lane l -> row 32w + l/4 (+16 for
  // 2nd inst), LDS slot chunk sq = l&3; fetch global chunk gq = sq ^ ((row>>1)&3).
  // (row>>1)&3 == (l>>3)&3 for both row and row+16 (16w and +8 are 0 mod 4).
  const int srow = wave * 32 + (lane >> 2);
  const int gq   = (lane & 3) ^ ((lane >> 3) & 3);
  const int scol = gq * 8;
  const bf16* gA0 = At + srow * 768 + scol;
  const bf16* gA1 = gA0 + 16 * 768;
  const bf16* gB0 = Bt + srow * 768 + scol;
  const bf16* gB1 = gB0 + 16 * 768;
  // LDS row-major [128][32] bf16; lane's 16B lands at base + lane*16B.
  bf16* sA0 = lA + wave * 1024 + lane * 8;
  bf16* sA1 = sA0 + 512;
  bf16* sB0 = lB + wave * 1024 + lane * 8;
  bf16* sB1 = sB0 + 512;

  const int wm = (wave & 1) * 64;
  const int wn = (wave >> 1) * 64;
  const int qg = lane >> 4;                 // k-chunk this quad wants
  const int sw = (l16 >> 1) & 3;            // row-swizzle (wm/wn are 0 mod 128 rows>>1 -> 0 mod 4)
  const int rdoff = ((qg ^ sw) * 8);        // element offset of swizzled chunk

  for (int kt = 0; kt < 768; kt += 32) {
    GL16(gA0 + kt, sA0);
    GL16(gA1 + kt, sA1);
    GL16(gB0 + kt, sB0);
    GL16(gB1 + kt, sB1);
    __syncthreads();   // drains vmcnt(0) then barrier: staged data visible

    bf16x8 aF[4], bF[4];
#pragma unroll
    for (int i = 0; i < 4; i++)
      aF[i] = *(const bf16x8*)(lA + (wm + i * 16 + l16) * 32 + rdoff);
#pragma unroll
    for (int j = 0; j < 4; j++)
      bF[j] = *(const bf16x8*)(lB + (wn + j * 16 + l16) * 32 + rdoff);

#pragma unroll
    for (int i = 0; i < 4; i++)
#pragma unroll
      for (int j = 0; j < 4; j++)
        acc[i][j] = __builtin_amdgcn_mfma_f32_16x16x32_bf16(aF[i], bF[j], acc[i][j], 0, 0, 0);

    __syncthreads();   // all waves done reading LDS before next stage overwrites
  }
}

// ---------------------------------------------------------------------------
// GEMM1: qkv[32768, 2304] bf16 = x_bf16[32768,768] @ w_qkv_bf16[2304,768]^T
// ---------------------------------------------------------------------------
__global__ __launch_bounds__(256) void gemm_qkv(const bf16* __restrict__ A,
                                                const bf16* __restrict__ B,
                                                bf16* __restrict__ C) {
  __shared__ __align__(16) bf16 lA[128 * 32];
  __shared__ __align__(16) bf16 lB[128 * 32];
  f32x4 acc[4][4] = {};

  const int m0 = blockIdx.x * 128;
  const int n0 = blockIdx.y * 128;
  gemm_core_768(A + (size_t)m0 * 768, B + (size_t)n0 * 768, lA, lB, acc);

  const int tid = threadIdx.x, wave = tid >> 6, lane = tid & 63;
  // C/D layout (16x16x32): col = lane&15, row = (lane>>4)*4 + reg
  const int row0 = m0 + (wave & 1) * 64 + (lane >> 4) * 4;
  const int col0 = n0 + (wave >> 1) * 64 + (lane & 15);
#pragma unroll
  for (int i = 0; i < 4; i++)
#pragma unroll
    for (int j = 0; j < 4; j++)
#pragma unroll
      for (int r = 0; r < 4; r++)
        C[(size_t)(row0 + i * 16 + r) * 2304 + col0 + j * 16] = (bf16)acc[i][j][r];
}

// ---------------------------------------------------------------------------
// modulator stage 1: partial[b, chunk, c*8+j] = sum over 64 rows of
//   p2[h,n] * k[b,n,c*8+j] * v[b,n,c*8+j],  c in [0,96), h = c>>3.
// grid (64, 8) = (n-chunk, b); 192 threads: c = t%96, row-parity rp = t/96.
// Fully coalesced bf16x8 loads (96 lanes cover a 1536B k-row).
// ---------------------------------------------------------------------------
__global__ __launch_bounds__(192) void mod_partial(const bf16* __restrict__ qkv,
                                                   const float* __restrict__ p2,
                                                   float* __restrict__ partials) {
  const int chunk = blockIdx.x, b = blockIdx.y;
  const int t = threadIdx.x;
  const int c  = t % 96;
  const int rp = t / 96;          // 0 or 1
  const int h  = c >> 3;
  const int n0 = chunk * 64;

  const bf16* kp  = qkv + ((size_t)(b * 4096 + n0 + rp)) * 2304 + 768 + c * 8;
  const float* pw = p2 + h * 4096 + n0 + rp;

  float acc[8] = {0.f, 0.f, 0.f, 0.f, 0.f, 0.f, 0.f, 0.f};
#pragma unroll 4
  for (int i = 0; i < 32; i++) {
    const bf16* kpi = kp + (size_t)i * 2 * 2304;
    const bf16x8 kv = *(const bf16x8*)(kpi);
    const bf16x8 vv = *(const bf16x8*)(kpi + 768);
    const float p = pw[2 * i];
#pragma unroll
    for (int j = 0; j < 8; j++)
      acc[j] += p * (float)kv[j] * (float)vv[j];
  }

  __shared__ float red[2][96][8];
#pragma unroll
  for (int j = 0; j < 8; j++) red[rp][c][j] = acc[j];
  __syncthreads();
  if (t < 96) {
    float* o = partials + ((size_t)(b * 64 + chunk)) * 768 + c * 8;
#pragma unroll
    for (int j = 0; j < 8; j++) o[j] = red[0][c][j] + red[1][c][j];
  }
}

// ---------------------------------------------------------------------------
// modulator stage 2: sum 64 chunk-partials, then LayerNorm over d (64 lanes).
// grid (12, 8) = (h, b); 64 threads, d = lane.
// ---------------------------------------------------------------------------
__global__ __launch_bounds__(64) void mod_reduce_ln(const float* __restrict__ partials,
                                                    const float* __restrict__ gamma,
                                                    const float* __restrict__ beta,
                                                    float* __restrict__ mod) {
  const int h = blockIdx.x, b = blockIdx.y;
  const int d = threadIdx.x;

  const float* p = partials + (size_t)(b * 64) * 768 + h * 64 + d;
  float s = 0.f;
#pragma unroll 8
  for (int chunk = 0; chunk < 64; chunk++) s += p[(size_t)chunk * 768];

  float sum = s, sumsq = s * s;
#pragma unroll
  for (int o = 32; o > 0; o >>= 1) {
    sum   += __shfl_xor(sum, o);
    sumsq += __shfl_xor(sumsq, o);
  }
  const float mu  = sum * (1.f / 64.f);
  const float var = sumsq * (1.f / 64.f) - mu * mu;
  const float r   = rsqrtf(var + LN_EPS);
  mod[(b * 12 + h) * 64 + d] = (s - mu) * r * gamma[d] + beta[d];
}

// ---------------------------------------------------------------------------
// a_mod[m, c] = q[m, c] * p1[h(c), n(m)] * mod[b(m), c]   (bf16 out)
// ---------------------------------------------------------------------------
__global__ __launch_bounds__(256) void modulate(const bf16* __restrict__ qkv,
                                                const float* __restrict__ p1,
                                                const float* __restrict__ mod,
                                                bf16* __restrict__ amod) {
  const int v = blockIdx.x * 256 + threadIdx.x;   // vec-8 index; total 32768*96
  if (v >= 32768 * 96) return;
  const int m  = v / 96;
  const int cv = v - m * 96;
  const int c0 = cv * 8;
  const int b  = m >> 12;
  const int n  = m & 4095;
  const int h  = c0 >> 6;

  const bf16x8 q = *(const bf16x8*)(qkv + (size_t)m * 2304 + c0);
  const float pv = p1[h * 4096 + n];
  const float4 m0 = *(const float4*)(mod + b * 768 + c0);
  const float4 m1 = *(const float4*)(mod + b * 768 + c0 + 4);

  bf16x8 o;
  o[0] = (bf16)((float)q[0] * pv * m0.x);
  o[1] = (bf16)((float)q[1] * pv * m0.y);
  o[2] = (bf16)((float)q[2] * pv * m0.z);
  o[3] = (bf16)((float)q[3] * pv * m0.w);
  o[4] = (bf16)((float)q[4] * pv * m1.x);
  o[5] = (bf16)((float)q[5] * pv * m1.y);
  o[6] = (bf16)((float)q[6] * pv * m1.z);
  o[7] = (bf16)((float)q[7] * pv * m1.w);
  *(bf16x8*)(amod + (size_t)m * 768 + c0) = o;
}

// ---------------------------------------------------------------------------
// GEMM2: out[32768,768] fp32 = a_mod[32768,768] @ w_proj_bf16[768,768]^T + b_proj
// ---------------------------------------------------------------------------
__global__ __launch_bounds__(256) void gemm_proj(const bf16* __restrict__ A,
                                                 const bf16* __restrict__ B,
                                                 const float* __restrict__ bias,
                                                 float* __restrict__ C) {
  __shared__ __align__(16) bf16 lA[128 * 32];
  __shared__ __align__(16) bf16 lB[128 * 32];
  f32x4 acc[4][4] = {};

  const int m0 = blockIdx.x * 128;
  const int n0 = blockIdx.y * 128;
  gemm_core_768(A + (size_t)m0 * 768, B + (size_t)n0 * 768, lA, lB, acc);

  const int tid = threadIdx.x, wave = tid >> 6, lane = tid & 63;
  const int row0 = m0 + (wave & 1) * 64 + (lane >> 4) * 4;
  const int col0 = n0 + (wave >> 1) * 64 + (lane & 15);
#pragma unroll
  for (int j = 0; j < 4; j++) {
    const int col = col0 + j * 16;
    const float bv = bias[col];
#pragma unroll
    for (int i = 0; i < 4; i++)
#pragma unroll
      for (int r = 0; r < 4; r++)
        C[(size_t)(row0 + i * 16 + r) * 768 + col] = acc[i][j][r] + bv;
  }
}

// ---------------------------------------------------------------------------
extern "C" void kernel_launch(void* const* d_in, const int* in_sizes, int n_in,
                              void* d_out, int out_size, void* d_ws, size_t ws_size,
                              hipStream_t stream) {
  (void)in_sizes; (void)n_in; (void)out_size; (void)ws_size;

  const float* x      = (const float*)d_in[0];   // [8,4096,768]
  const float* w_qkv  = (const float*)d_in[1];   // [2304,768]
  const float* w_proj = (const float*)d_in[2];   // [768,768]
  const float* b_proj = (const float*)d_in[3];   // [768]
  const float* p1     = (const float*)d_in[4];   // [12,4096]
  const float* p2     = (const float*)d_in[5];   // [12,4096]
  const float* gamma  = (const float*)d_in[6];   // [64]
  const float* beta   = (const float*)d_in[7];   // [64]
  float* out = (float*)d_out;                    // [8,4096,768] fp32

  char* ws = (char*)d_ws;
  // workspace layout (bytes); total ~206 MB (same proven bound as R1)
  bf16*  xb   = (bf16*)(ws + 0);                  // 50,331,648  x bf16 [32768,768]
  bf16*  wqb  = (bf16*)(ws + 50331648);           //  3,538,944  w_qkv bf16 [2304,768]
  bf16*  wpb  = (bf16*)(ws + 53870592);           //  1,179,648  w_proj bf16 [768,768]
  bf16*  qkv  = (bf16*)(ws + 55050240);           // 150,994,944 qkv bf16 [32768,2304]
  float* mod  = (float*)(ws + 206045184);         //     24,576  mod fp32 [8,12,64]
  // partials [8*64][768] fp32 = 1.57MB reuses the xb region (dead between
  // gemm_qkv and modulate; stream order guarantees safety).
  float* partials = (float*)(ws + 0);
  bf16*  amod     = (bf16*)(ws + 0);              // reuses xb region after reduce

  // 1) fp32 -> bf16 conversions
  cvt_kernel<<<24576, 256, 0, stream>>>(x, xb, 6291456);
  cvt_kernel<<<1728,  256, 0, stream>>>(w_qkv, wqb, 442368);
  cvt_kernel<<<576,   256, 0, stream>>>(w_proj, wpb, 147456);

  // 2) QKV GEMM: [32768,768] x [2304,768]^T -> [32768,2304] bf16
  gemm_qkv<<<dim3(256, 18), 256, 0, stream>>>(xb, wqb, qkv);

  // 3) modulator: split-N partial reduce, then reduce + LayerNorm
  mod_partial<<<dim3(64, 8), 192, 0, stream>>>(qkv, p2, partials);
  mod_reduce_ln<<<dim3(12, 8), 64, 0, stream>>>(partials, gamma, beta, mod);

  // 4) a_mod = q * p1 * mod (bf16), overwrites partials/xb region
  modulate<<<12288, 256, 0, stream>>>(qkv, p1, mod, amod);

  // 5) proj GEMM + bias: [32768,768] x [768,768]^T -> out fp32
  gemm_proj<<<dim3(256, 6), 256, 0, stream>>>(amod, wpb, b_proj, out);
}

// Round 3
// 408.388 us; speedup vs baseline: 1.1523x; 1.0681x over previous
//
#include <hip/hip_runtime.h>
#include <stdint.h>
#include <stddef.h>

#define LN_EPS 1e-5f

typedef __bf16 bf16;
typedef __bf16 bf16x8 __attribute__((ext_vector_type(8)));
typedef __bf16 bf16x4 __attribute__((ext_vector_type(4)));
typedef float f32x4 __attribute__((ext_vector_type(4)));

// async global->LDS, 16B per lane. LDS dest must be wave-uniform base + lane*16.
#define GL16(gp, lp)                                                                   \
  __builtin_amdgcn_global_load_lds((__attribute__((address_space(1))) uint32_t*)(gp),  \
                                   (__attribute__((address_space(3))) uint32_t*)(lp),  \
                                   16, 0, 0)

// ---------------------------------------------------------------------------
// single fp32 -> bf16 convert kernel for all three tensors (one launch)
// ---------------------------------------------------------------------------
#define XV4   6291456           // x:      25,165,824 f32 / 4
#define WQV4  442368            // w_qkv:   1,769,472 f32 / 4
#define WPV4  147456            // w_proj:    589,824 f32 / 4
__global__ __launch_bounds__(256) void cvt_all(const float* __restrict__ x,
                                               const float* __restrict__ wq,
                                               const float* __restrict__ wp,
                                               bf16* __restrict__ xb,
                                               bf16* __restrict__ wqb,
                                               bf16* __restrict__ wpb) {
  int i = blockIdx.x * 256 + threadIdx.x;
  const float* src; bf16* dst; int off;
  if (i < XV4)              { src = x;  dst = xb;  off = i; }
  else if (i < XV4 + WQV4)  { src = wq; dst = wqb; off = i - XV4; }
  else                      { src = wp; dst = wpb; off = i - (XV4 + WQV4); }
  const float4 v = ((const float4*)src)[off];
  bf16x4 o;
  o[0] = (bf16)v.x; o[1] = (bf16)v.y; o[2] = (bf16)v.z; o[3] = (bf16)v.w;
  ((bf16x4*)dst)[off] = o;
}

// ---------------------------------------------------------------------------
// Shared GEMM core: C[128x128] tile, A row-major [.,768], B row-major [.,768]
// (B^T GEMM). K=768, BK=32. 256 thr = 4 waves, 4x4 mfma_f32_16x16x32_bf16.
// Bt may be a per-wave-adjusted base (kv kernel splices k and v row ranges);
// core addresses Bt + srow*768 with srow = wave*32 + lane/4.
// XOR bank swizzle on LDS chunks: slot (r,q) holds global chunk q^((r>>1)&3).
// ---------------------------------------------------------------------------
__device__ __forceinline__ void gemm_core_768(const bf16* At, const bf16* Bt,
                                              bf16* lA, bf16* lB,
                                              f32x4 acc[4][4]) {
  const int tid  = threadIdx.x;
  const int wave = tid >> 6;
  const int lane = tid & 63;
  const int l16  = lane & 15;

  const int srow = wave * 32 + (lane >> 2);
  const int gq   = (lane & 3) ^ ((lane >> 3) & 3);
  const int scol = gq * 8;
  const bf16* gA0 = At + srow * 768 + scol;
  const bf16* gA1 = gA0 + 16 * 768;
  const bf16* gB0 = Bt + srow * 768 + scol;
  const bf16* gB1 = gB0 + 16 * 768;
  bf16* sA0 = lA + wave * 1024 + lane * 8;
  bf16* sA1 = sA0 + 512;
  bf16* sB0 = lB + wave * 1024 + lane * 8;
  bf16* sB1 = sB0 + 512;

  const int wm = (wave & 1) * 64;
  const int wn = (wave >> 1) * 64;
  const int qg = lane >> 4;
  const int sw = (l16 >> 1) & 3;
  const int rdoff = ((qg ^ sw) * 8);

  for (int kt = 0; kt < 768; kt += 32) {
    GL16(gA0 + kt, sA0);
    GL16(gA1 + kt, sA1);
    GL16(gB0 + kt, sB0);
    GL16(gB1 + kt, sB1);
    __syncthreads();

    bf16x8 aF[4], bF[4];
#pragma unroll
    for (int i = 0; i < 4; i++)
      aF[i] = *(const bf16x8*)(lA + (wm + i * 16 + l16) * 32 + rdoff);
#pragma unroll
    for (int j = 0; j < 4; j++)
      bF[j] = *(const bf16x8*)(lB + (wn + j * 16 + l16) * 32 + rdoff);

#pragma unroll
    for (int i = 0; i < 4; i++)
#pragma unroll
      for (int j = 0; j < 4; j++)
        acc[i][j] = __builtin_amdgcn_mfma_f32_16x16x32_bf16(aF[i], bF[j], acc[i][j], 0, 0, 0);

    __syncthreads();
  }
}

// ---------------------------------------------------------------------------
// Pass 1: k/v GEMM + fused p2-weighted k*v reduction. Grid (12 h, 256 mblk).
// Block computes C[128 n-rows][128 cols] where cols 0..63 = k head h,
// 64..127 = v head h (B rows spliced per wave). Epilogue: acc -> bf16 in
// padded LDS, reduce sum_n p2[h,n]*k*v -> partials[mblk][h][64].
// k and v never touch HBM.
// ---------------------------------------------------------------------------
__global__ __launch_bounds__(256) void kv_gemm_reduce(const bf16* __restrict__ A,
                                                      const bf16* __restrict__ B,
                                                      const float* __restrict__ p2,
                                                      float* __restrict__ partials) {
  // 34,816B k/v tile store (bf16 [2][128][68] padded) aliased over the 16KB
  // staging buffers (dead after the core's final barrier), + 1KB reduce buf.
  __shared__ __align__(16) bf16 sKV[2 * 128 * 68];
  __shared__ float red[4][64];
  bf16* lA = sKV;
  bf16* lB = sKV + 4096;

  const int h    = blockIdx.x;
  const int mblk = blockIdx.y;
  const int m0   = mblk * 128;
  const int tid  = threadIdx.x, wave = tid >> 6, lane = tid & 63;

  // waves 0,1 stage k rows (w_qkv rows 768+64h ..+64); waves 2,3 stage v rows
  // (1536+64h ..+64). Core uses srow = wave*32+., so pre-bias v base by -64 rows.
  const bf16* Bt = B + (size_t)(wave < 2 ? (768 + h * 64) : (1536 + h * 64 - 64)) * 768;

  f32x4 acc[4][4] = {};
  gemm_core_768(A + (size_t)m0 * 768, Bt, lA, lB, acc);

  // ---- epilogue: spill tiles to LDS as bf16 (same quantization as the old
  // qkv-materializing path), padded stride 68 for conflict-free writes.
  const int kv    = wave >> 1;                      // 0 = k, 1 = v
  const int row_l = (wave & 1) * 64 + (lane >> 4) * 4;
  const int d_l   = lane & 15;
  bf16* sT = sKV + kv * (128 * 68);
#pragma unroll
  for (int i = 0; i < 4; i++)
#pragma unroll
    for (int j = 0; j < 4; j++)
#pragma unroll
      for (int r = 0; r < 4; r++)
        sT[(row_l + i * 16 + r) * 68 + j * 16 + d_l] = (bf16)acc[i][j][r];
  __syncthreads();

  // ---- reduce over the 128 rows: thread (d = tid&63, chunk = tid>>6) sums 32
  const int d  = tid & 63;
  const int ch = tid >> 6;
  const int n_base = (m0 & 4095) + ch * 32;
  const float* pw = p2 + h * 4096 + n_base;
  const bf16* sk = sKV + (ch * 32) * 68 + d;
  const bf16* sv = sk + 128 * 68;
  float s = 0.f;
#pragma unroll 8
  for (int n = 0; n < 32; n++)
    s += pw[n] * (float)sk[n * 68] * (float)sv[n * 68];
  red[ch][d] = s;
  __syncthreads();
  if (tid < 64) {
    partials[((size_t)mblk * 12 + h) * 64 + tid] =
        red[0][tid] + red[1][tid] + red[2][tid] + red[3][tid];
  }
}

// ---------------------------------------------------------------------------
// Stage 2: sum the 32 per-mblk partials of each batch, then LayerNorm over d.
// grid (12 h, 8 b); 64 threads, d = lane.
// ---------------------------------------------------------------------------
__global__ __launch_bounds__(64) void mod_reduce_ln(const float* __restrict__ partials,
                                                    const float* __restrict__ gamma,
                                                    const float* __restrict__ beta,
                                                    float* __restrict__ mod) {
  const int h = blockIdx.x, b = blockIdx.y;
  const int d = threadIdx.x;

  const float* p = partials + ((size_t)(b * 32) * 12 + h) * 64 + d;
  float s = 0.f;
#pragma unroll 8
  for (int mb = 0; mb < 32; mb++) s += p[(size_t)mb * 12 * 64];

  float sum = s, sumsq = s * s;
#pragma unroll
  for (int o = 32; o > 0; o >>= 1) {
    sum   += __shfl_xor(sum, o);
    sumsq += __shfl_xor(sumsq, o);
  }
  const float mu  = sum * (1.f / 64.f);
  const float var = sumsq * (1.f / 64.f) - mu * mu;
  const float r   = rsqrtf(var + LN_EPS);
  mod[(b * 12 + h) * 64 + d] = (s - mu) * r * gamma[d] + beta[d];
}

// ---------------------------------------------------------------------------
// Pass 2: q GEMM + fused modulation. Grid (6 nblk, 256 mblk).
// amod[m, c] = q[m, c] * p1[h(c), n(m)] * mod[b(m), c]  (bf16 out)
// ---------------------------------------------------------------------------
__global__ __launch_bounds__(256) void q_gemm_mod(const bf16* __restrict__ A,
                                                  const bf16* __restrict__ B,
                                                  const float* __restrict__ p1,
                                                  const float* __restrict__ mod,
                                                  bf16* __restrict__ amod) {
  __shared__ __align__(16) bf16 lA[128 * 32];
  __shared__ __align__(16) bf16 lB[128 * 32];
  f32x4 acc[4][4] = {};

  const int n0 = blockIdx.x * 128;
  const int m0 = blockIdx.y * 128;
  gemm_core_768(A + (size_t)m0 * 768, B + (size_t)n0 * 768, lA, lB, acc);

  const int tid = threadIdx.x, wave = tid >> 6, lane = tid & 63;
  const int row0 = m0 + (wave & 1) * 64 + (lane >> 4) * 4;
  const int col0 = n0 + (wave >> 1) * 64 + (lane & 15);
  const int b    = m0 >> 12;
  const int h    = (n0 + (wave >> 1) * 64) >> 6;   // wave-uniform head

  float p1v[4][4];
#pragma unroll
  for (int i = 0; i < 4; i++)
#pragma unroll
    for (int r = 0; r < 4; r++)
      p1v[i][r] = p1[h * 4096 + ((row0 + i * 16 + r) & 4095)];
  float mv[4];
#pragma unroll
  for (int j = 0; j < 4; j++) mv[j] = mod[b * 768 + col0 + j * 16];

#pragma unroll
  for (int i = 0; i < 4; i++)
#pragma unroll
    for (int j = 0; j < 4; j++)
#pragma unroll
      for (int r = 0; r < 4; r++)
        amod[(size_t)(row0 + i * 16 + r) * 768 + col0 + j * 16] =
            (bf16)(acc[i][j][r] * p1v[i][r] * mv[j]);
}

// ---------------------------------------------------------------------------
// Pass 3: out[32768,768] fp32 = amod @ w_proj_bf16^T + b_proj. Grid (6, 256).
// ---------------------------------------------------------------------------
__global__ __launch_bounds__(256) void gemm_proj(const bf16* __restrict__ A,
                                                 const bf16* __restrict__ B,
                                                 const float* __restrict__ bias,
                                                 float* __restrict__ C) {
  __shared__ __align__(16) bf16 lA[128 * 32];
  __shared__ __align__(16) bf16 lB[128 * 32];
  f32x4 acc[4][4] = {};

  const int n0 = blockIdx.x * 128;
  const int m0 = blockIdx.y * 128;
  gemm_core_768(A + (size_t)m0 * 768, B + (size_t)n0 * 768, lA, lB, acc);

  const int tid = threadIdx.x, wave = tid >> 6, lane = tid & 63;
  const int row0 = m0 + (wave & 1) * 64 + (lane >> 4) * 4;
  const int col0 = n0 + (wave >> 1) * 64 + (lane & 15);
#pragma unroll
  for (int j = 0; j < 4; j++) {
    const int col = col0 + j * 16;
    const float bv = bias[col];
#pragma unroll
    for (int i = 0; i < 4; i++)
#pragma unroll
      for (int r = 0; r < 4; r++)
        C[(size_t)(row0 + i * 16 + r) * 768 + col] = acc[i][j][r] + bv;
  }
}

// ---------------------------------------------------------------------------
extern "C" void kernel_launch(void* const* d_in, const int* in_sizes, int n_in,
                              void* d_out, int out_size, void* d_ws, size_t ws_size,
                              hipStream_t stream) {
  (void)in_sizes; (void)n_in; (void)out_size; (void)ws_size;

  const float* x      = (const float*)d_in[0];   // [8,4096,768]
  const float* w_qkv  = (const float*)d_in[1];   // [2304,768]
  const float* w_proj = (const float*)d_in[2];   // [768,768]
  const float* b_proj = (const float*)d_in[3];   // [768]
  const float* p1     = (const float*)d_in[4];   // [12,4096]
  const float* p2     = (const float*)d_in[5];   // [12,4096]
  const float* gamma  = (const float*)d_in[6];   // [64]
  const float* beta   = (const float*)d_in[7];   // [64]
  float* out = (float*)d_out;                    // [8,4096,768] fp32

  char* ws = (char*)d_ws;
  // workspace layout (bytes); total ~107 MB
  bf16*  xb       = (bf16*)(ws + 0);              // 50,331,648  x bf16 [32768,768]
  bf16*  wqb      = (bf16*)(ws + 50331648);       //  3,538,944  w_qkv bf16
  bf16*  wpb      = (bf16*)(ws + 53870592);       //  1,179,648  w_proj bf16
  bf16*  amod     = (bf16*)(ws + 55050240);       // 50,331,648  amod bf16 [32768,768]
  float* partials = (float*)(ws + 105381888);     //    786,432  [256][12][64] f32
  float* mod      = (float*)(ws + 106168320);     //     24,576  [8][12][64] f32

  // 1) all fp32 -> bf16 conversions in one launch (26,880 blocks exact)
  cvt_all<<<26880, 256, 0, stream>>>(x, w_qkv, w_proj, xb, wqb, wpb);

  // 2) k/v GEMM + fused p2*k*v reduction (k,v never written to HBM)
  kv_gemm_reduce<<<dim3(12, 256), 256, 0, stream>>>(xb, wqb, p2, partials);

  // 3) finish reduction + LayerNorm -> mod [8,12,64]
  mod_reduce_ln<<<dim3(12, 8), 64, 0, stream>>>(partials, gamma, beta, mod);

  // 4) q GEMM + fused p1/mod modulation -> amod bf16
  q_gemm_mod<<<dim3(6, 256), 256, 0, stream>>>(xb, wqb, p1, mod, amod);

  // 5) proj GEMM + bias -> out fp32
  gemm_proj<<<dim3(6, 256), 256, 0, stream>>>(amod, wpb, b_proj, out);
}